// Round 12
// baseline (373.607 us; speedup 1.0000x reference)
//
#include <hip/hip_runtime.h>

#define NB 62
#define NC 5
#define KTOP 49

typedef unsigned short ushort_t;
typedef unsigned int uint_t;

__device__ __forceinline__ float sigmf(float x) {
    return 1.0f / (1.0f + __expf(-x));
}

__device__ __forceinline__ ushort_t f2b(float f) {   // f32 -> bf16 (RNE)
    union { float f; uint_t u; } cv; cv.f = f;
    uint_t r = (cv.u + 0x7fffu + ((cv.u >> 16) & 1u)) >> 16;
    return (ushort_t)r;
}
__device__ __forceinline__ float bits2f(uint_t u) {
    union { uint_t u; float f; } cv; cv.u = u; return cv.f;
}

__device__ __forceinline__ float tmax16(const float* a) {
    float t0 = fmaxf(a[0], a[4]), t1 = fmaxf(a[1], a[5]);
    float t2 = fmaxf(a[2], a[6]), t3 = fmaxf(a[3], a[7]);
    t0 = fmaxf(t0, fmaxf(a[8], a[12]));  t1 = fmaxf(t1, fmaxf(a[9], a[13]));
    t2 = fmaxf(t2, fmaxf(a[10], a[14])); t3 = fmaxf(t3, fmaxf(a[11], a[15]));
    return fmaxf(fmaxf(t0, t1), fmaxf(t2, t3));
}
__device__ __forceinline__ float tsum16(const float* a) {
    float t0 = a[0] + a[4], t1 = a[1] + a[5], t2 = a[2] + a[6], t3 = a[3] + a[7];
    t0 += a[8] + a[12]; t1 += a[9] + a[13]; t2 += a[10] + a[14]; t3 += a[11] + a[15];
    return (t0 + t1) + (t2 + t3);
}

// ascending bitonic sort of 16 register-resident floats
__device__ __forceinline__ void sort16(float* s) {
    #pragma unroll
    for (int k = 2; k <= 16; k <<= 1) {
        #pragma unroll
        for (int j = k >> 1; j > 0; j >>= 1) {
            #pragma unroll
            for (int i = 0; i < 16; ++i) {
                const int p = i ^ j;
                if (p > i) {
                    const bool up = ((i & k) == 0);
                    const float a = s[i], c = s[p];
                    s[i] = up ? fminf(a, c) : fmaxf(a, c);
                    s[p] = up ? fmaxf(a, c) : fminf(a, c);
                }
            }
        }
    }
}
// m asc, b asc -> m = 16 smallest of union, ascending (unique multiset result;
// reversed-operand lane computes the reversed bitonic vector, which the merge
// network sorts to the same ascending output -> bitwise-identical both lanes)
__device__ __forceinline__ void merge_low16(float* m, const float* b) {
    float t[16];
    #pragma unroll
    for (int i = 0; i < 16; ++i) t[i] = fminf(m[i], b[15 - i]);
    #pragma unroll
    for (int j = 8; j > 0; j >>= 1) {
        #pragma unroll
        for (int i = 0; i < 16; ++i) {
            const int p = i ^ j;
            if (p > i) {
                const float a = t[i], c = t[p];
                t[i] = fminf(a, c);
                t[p] = fmaxf(a, c);
            }
        }
    }
    #pragma unroll
    for (int i = 0; i < 16; ++i) m[i] = t[i];
}

// Repack FC weights (f32, no unpack ops in main kernel):
// fc1w[64][930] -> [30][256][8]: [j][t][e] = fc1w[t>>2][ (t&3)*240 + j*8 + e ]
// (zero-pad past 929; 4*240=960 covers 930).
// fc2w[64][64]  -> [4][256][4]:  [j][t][e] = fc2w[t>>2][ (t&3)*16 + j*4 + e ]
__global__ void repack_kernel(const float* __restrict__ fc1w,
                              const float* __restrict__ fc2w,
                              float* __restrict__ w1o,
                              float* __restrict__ w2o) {
    const int i = blockIdx.x * 256 + threadIdx.x;
    if (i < 30 * 256 * 8) {
        const int e = i & 7, t = (i >> 3) & 255, j = i >> 11;
        const int o = t >> 2, h2 = t & 3;
        const int f = h2 * 240 + j * 8 + e;
        w1o[i] = (f < 930) ? fc1w[o * 930 + f] : 0.0f;
    } else if (i < 30 * 256 * 8 + 4 * 256 * 4) {
        const int i2 = i - 30 * 256 * 8;
        const int e = i2 & 3, t = (i2 >> 2) & 255, j = i2 >> 10;
        const int o = t >> 2, h2 = t & 3;
        w2o[i2] = fc2w[o * 64 + h2 * 16 + j * 4 + e];
    }
}

// One DGCN layer, quad-split rows (thread (n,q) owns elements q*16+i, i<16;
// q==3 has 14 real + 2 pads). L==0: input xin_g; out -> s_xout. L==1: s_xin.
template <int L>
__device__ __forceinline__ void dgcn_layer(
    const int tid, const float* __restrict__ xin_g,
    const float* __restrict__ conv_w, const float* __restrict__ conv_b,
    const float* __restrict__ memp,
    const float* __restrict__ gfc_w, const float* __restrict__ gfc_b,
    const float* __restrict__ gcn_w, const float* __restrict__ gcn_b,
    float (*__restrict__ s_xc4)[4], float* __restrict__ s_xc1,
    float (*__restrict__ s_me4)[4], float* __restrict__ s_me1,
    uint_t* __restrict__ s_adj32,
    float (*__restrict__ s_xin)[NC], float (*__restrict__ s_xout)[NC])
{
    const float scale = 0.44721359549995793f; // 1/sqrt(5)
    const int n = tid >> 2, q = tid & 3;
    const int q16 = q * 16;

    // stage mem: 310 floats > 256 threads -> MUST be a strided loop
    // (round-11 bug: single guarded store left s_me1[8..61] unstaged)
    for (int i = tid; i < NC * NB; i += 256) {
        const int c = i / NB, m = i - c * NB;
        if (c < 4) s_me4[m][c] = memp[i];
        else       s_me1[m]    = memp[i];
    }

    // ---- conv1x1: threads 0..61 (wave 0), node = tid ----
    if (tid < NB) {
        float cw[25], cbv[5];
        #pragma unroll
        for (int i = 0; i < 25; ++i) cw[i] = conv_w[i];
        #pragma unroll
        for (int i = 0; i < 5; ++i)  cbv[i] = conv_b[i];
        float xn[5];
        #pragma unroll
        for (int c = 0; c < 5; ++c)
            xn[c] = (L == 0) ? xin_g[c * NB + tid] : s_xin[tid][c];
        float xo[5];
        #pragma unroll
        for (int o = 0; o < 5; ++o) {
            float a = cbv[o];
            #pragma unroll
            for (int c = 0; c < 5; ++c) a = fmaf(cw[o * 5 + c], xn[c], a);
            xo[o] = a;
        }
        s_xc4[tid][0] = xo[0]; s_xc4[tid][1] = xo[1];
        s_xc4[tid][2] = xo[2]; s_xc4[tid][3] = xo[3];
        s_xc1[tid] = xo[4];
    }
    __syncthreads();

    // ---- row phase ----
    if (n < NB) {
        const float4 xo03 = *(const float4*)&s_xc4[n][0];
        const float  xo4  = s_xc1[n];
        float r1[16], r2[16];
        #pragma unroll
        for (int i = 0; i < 16; ++i) {
            const int m = q16 + i;
            const bool valid = (i < 14) || (q < 3);
            const int mm = valid ? m : 0;
            const float4 xc03 = *(const float4*)&s_xc4[mm][0];
            const float  xc4  = s_xc1[mm];
            const float4 me03 = *(const float4*)&s_me4[mm][0];
            const float  me4  = s_me1[mm];
            float s1 = xo03.x * me03.x + xo03.y * me03.y + xo03.z * me03.z +
                       xo03.w * me03.w + xo4 * me4;
            float s2 = xo03.x * xc03.x + xo03.y * xc03.y + xo03.z * xc03.z +
                       xo03.w * xc03.w + xo4 * xc4;
            r1[i] = valid ? fmaxf(s1 * scale, 0.0f) : -INFINITY;
            r2[i] = valid ? fmaxf(s2 * scale, 0.0f) : -INFINITY;
        }
        // softmax(r1): quad-combined (pads -INF -> exp 0)
        float mx1 = tmax16(r1);
        mx1 = fmaxf(mx1, __shfl_xor(mx1, 1, 64));
        mx1 = fmaxf(mx1, __shfl_xor(mx1, 2, 64));
        #pragma unroll
        for (int i = 0; i < 16; ++i) r1[i] = __expf(r1[i] - mx1);
        float sm1 = tsum16(r1);
        sm1 += __shfl_xor(sm1, 1, 64);
        sm1 += __shfl_xor(sm1, 2, 64);
        // softmax(r2)
        float mx2 = tmax16(r2);
        mx2 = fmaxf(mx2, __shfl_xor(mx2, 1, 64));
        mx2 = fmaxf(mx2, __shfl_xor(mx2, 2, 64));
        #pragma unroll
        for (int i = 0; i < 16; ++i) r2[i] = __expf(r2[i] - mx2);
        float sm2 = tsum16(r2);
        sm2 += __shfl_xor(sm2, 1, 64);
        sm2 += __shfl_xor(sm2, 2, 64);
        // af = w0*a1 + w1*a2 + b0 (inv folded into scalars); r2 dies
        const float w0s = gfc_w[0] / sm1, w1s = gfc_w[1] / sm2, b0 = gfc_b[0];
        #pragma unroll
        for (int i = 0; i < 16; ++i)
            r1[i] = fmaf(r1[i], w0s, fmaf(r2[i], w1s, b0));
        if (q == 3) { r1[14] = -INFINITY; r1[15] = -INFINITY; }  // pads
        // softmax(af), normalized (ranking sees normalized values)
        float mxa = tmax16(r1);
        mxa = fmaxf(mxa, __shfl_xor(mxa, 1, 64));
        mxa = fmaxf(mxa, __shfl_xor(mxa, 2, 64));
        #pragma unroll
        for (int i = 0; i < 16; ++i) r1[i] = __expf(r1[i] - mxa);
        float sma = tsum16(r1);
        sma += __shfl_xor(sma, 1, 64);
        sma += __shfl_xor(sma, 2, 64);
        const float inva = 1.0f / sma;
        #pragma unroll
        for (int i = 0; i < 16; ++i) r1[i] *= inva;   // pads: 0.0

        // ---- 14th smallest of 62 (=49th largest), exact:
        //      own sort16 (pads -> +INF) + 2 cross-lane keep-low-16 merges ----
        float ga[16], gb[16];
        #pragma unroll
        for (int i = 0; i < 16; ++i) ga[i] = r1[i];
        if (q == 3) { ga[14] = INFINITY; ga[15] = INFINITY; }
        sort16(ga);
        #pragma unroll
        for (int i = 0; i < 16; ++i) gb[i] = __shfl_xor(ga[i], 1, 64);
        merge_low16(ga, gb);
        #pragma unroll
        for (int i = 0; i < 16; ++i) gb[i] = __shfl_xor(ga[i], 2, 64);
        merge_low16(ga, gb);
        const float vth = ga[13];   // identical on all 4 lanes

        // ---- tie-aware selection == jax.lax.top_k (lower index first) ----
        // (pads are 0.0 < vth and never equal vth>0 -> auto-excluded)
        int gt = 0, eqo = 0;
        #pragma unroll
        for (int i = 0; i < 16; ++i) {
            gt  += (r1[i] > vth);
            eqo += (r1[i] == vth);
        }
        int Gt = gt + __shfl_xor(gt, 1, 64);
        Gt += __shfl_xor(Gt, 2, 64);
        // exclusive prefix of eq over the quad (ascending m order)
        const int s1e = __shfl_xor(eqo, 1, 64);
        const int pre1 = (q & 1) ? s1e : 0;
        const int tp = eqo + s1e;
        const int s2e = __shfl_xor(tp, 2, 64);
        const int pre2 = (q & 2) ? s2e : 0;
        int eq = pre1 + pre2;

        uint_t pend = 0;
        #pragma unroll
        for (int i = 0; i < 16; ++i) {
            const bool e  = (r1[i] == vth);
            const bool ss = (r1[i] > vth) || (e && (Gt + eq) < KTOP);
            const uint_t hb = (uint_t)f2b(ss ? r1[i] : 0.0f);
            eq += e ? 1 : 0;
            if (i & 1) {
                if (i < 14 || q < 3)   // q==3 dword 7 = both pads, skip
                    s_adj32[n * 33 + q * 8 + (i >> 1)] = pend | (hb << 16);
            } else {
                pend = hb;
            }
        }
    }
    __syncthreads();

    // ---- diffusion + gcn mix + skip: quad handles column m=n, split over nn ----
    if (n < NB) {
        const int m = n;
        const int dw = m >> 1;
        const uint_t sh = (m & 1) ? 16u : 0u;
        float y0 = 0, y1 = 0, y2 = 0, y3 = 0, y4 = 0;
        #pragma unroll
        for (int j = 0; j < 16; ++j) {
            const int nn = q16 + j;
            const bool v2 = (j < 14) || (q < 3);
            const int nnc = v2 ? nn : 0;
            const uint_t w = s_adj32[nnc * 33 + dw];   // stride 33: 2-way max
            float a = bits2f((w >> sh) << 16);
            a = v2 ? a : 0.0f;
            const float4 xv = *(const float4*)&s_xc4[nnc][0];
            const float  xv4 = s_xc1[nnc];
            y0 = fmaf(xv.x, a, y0); y1 = fmaf(xv.y, a, y1); y2 = fmaf(xv.z, a, y2);
            y3 = fmaf(xv.w, a, y3); y4 = fmaf(xv4, a, y4);
        }
        y0 += __shfl_xor(y0, 1, 64); y0 += __shfl_xor(y0, 2, 64);
        y1 += __shfl_xor(y1, 1, 64); y1 += __shfl_xor(y1, 2, 64);
        y2 += __shfl_xor(y2, 1, 64); y2 += __shfl_xor(y2, 2, 64);
        y3 += __shfl_xor(y3, 1, 64); y3 += __shfl_xor(y3, 2, 64);
        y4 += __shfl_xor(y4, 1, 64); y4 += __shfl_xor(y4, 2, 64);
        if (q == 0) {
            float gwv[25], gbv[5];
            #pragma unroll
            for (int i = 0; i < 25; ++i) gwv[i] = gcn_w[i];
            #pragma unroll
            for (int i = 0; i < 5; ++i)  gbv[i] = gcn_b[i];
            #pragma unroll
            for (int o = 0; o < 5; ++o) {
                const float z = gbv[o] + gwv[o * 5 + 0] * y0 + gwv[o * 5 + 1] * y1 +
                                gwv[o * 5 + 2] * y2 + gwv[o * 5 + 3] * y3 + gwv[o * 5 + 4] * y4;
                const float fi = (L == 0) ? xin_g[o * NB + m] : s_xin[m][o];
                s_xout[m][o] = z + fi;
            }
        }
    }
    __syncthreads();
}

// 256 threads (4 waves), quad-split rows: peak live ~70 regs.
__global__ void __launch_bounds__(256) __attribute__((amdgpu_waves_per_eu(2, 6)))
encoder_kernel(
    const float* __restrict__ g_x,
    const float* __restrict__ c0w, const float* __restrict__ c0b,
    const float* __restrict__ m0,  const float* __restrict__ f0w,
    const float* __restrict__ f0b, const float* __restrict__ g0w,
    const float* __restrict__ g0b,
    const float* __restrict__ c1w, const float* __restrict__ c1b,
    const float* __restrict__ m1,  const float* __restrict__ f1w,
    const float* __restrict__ f1b, const float* __restrict__ g1w,
    const float* __restrict__ g1b,
    const float* __restrict__ caw1, const float* __restrict__ caw2,
    const float* __restrict__ saw,  const float* __restrict__ sab,
    const float* __restrict__ fc1w, const float* __restrict__ fc1b,
    const float* __restrict__ fc2w, const float* __restrict__ fc2b,
    const float* __restrict__ w1p, const float* __restrict__ w2p,
    const int use_ws,
    float* __restrict__ g_out)
{
    const int b   = blockIdx.x;
    const int tid = threadIdx.x;

    // LDS: 992+248 + 992+248 + 8184 (62*33 dwords) + 1240 + 1240 = 13144 B
    __shared__ __align__(16) float s_xc4[NB][4];
    __shared__ __align__(16) float s_xc1[NB];
    __shared__ __align__(16) float s_me4[NB][4];
    __shared__ __align__(16) float s_me1[NB];
    __shared__ __align__(16) uint_t s_adj32[NB * 33];
    __shared__ __align__(16) float s_x1[NB][NC];
    __shared__ __align__(16) float s_x2[NB][NC];

    float* const s_g  = (float*)s_adj32;          // 960 f32 alias (adj dead)
    float* const s_h1 = ((float*)s_adj32) + 960;  // 64 f32

    const float* xin = g_x + (size_t)b * (NC * NB);

    dgcn_layer<0>(tid, xin, c0w, c0b, m0, f0w, f0b, g0w, g0b,
                  s_xc4, s_xc1, s_me4, s_me1, s_adj32, nullptr, s_x1);
    dgcn_layer<1>(tid, xin, c1w, c1b, m1, f1w, f1b, g1w, g1b,
                  s_xc4, s_xc1, s_me4, s_me1, s_adj32, s_x1, s_x2);

    // ================= CBAM (wave 0: node = tid) ========
    float f0[5], f1v[5], f2v[5];
    #pragma unroll
    for (int c = 0; c < 5; ++c) {
        f0[c]  = (tid < NB) ? xin[c * NB + tid] : 0.0f;
        f1v[c] = (tid < NB) ? s_x1[tid][c] : 0.0f;
        f2v[c] = (tid < NB) ? s_x2[tid][c] : 0.0f;
    }
    float mxp[15], avp[15];
    #pragma unroll
    for (int c = 0; c < 15; ++c) {
        const float v = (c < 5) ? f0[c] : (c < 10) ? f1v[c - 5] : f2v[c - 10];
        float vm = (tid < NB) ? v : -INFINITY;
        float vs = (tid < NB) ? v : 0.0f;
        #pragma unroll
        for (int off = 32; off > 0; off >>= 1) {
            vm = fmaxf(vm, __shfl_xor(vm, off, 64));
            vs += __shfl_xor(vs, off, 64);
        }
        mxp[c] = vm;
        avp[c] = vs * (1.0f / 62.0f);
    }
    float ca[15];
    {
        float hm[3], ha[3];
        #pragma unroll
        for (int o = 0; o < 3; ++o) {
            float am = 0.0f, aa = 0.0f;
            #pragma unroll
            for (int c = 0; c < 15; ++c) {
                const float w = caw1[o * 15 + c];
                am = fmaf(mxp[c], w, am);
                aa = fmaf(avp[c], w, aa);
            }
            hm[o] = fmaxf(am, 0.0f);
            ha[o] = fmaxf(aa, 0.0f);
        }
        #pragma unroll
        for (int c = 0; c < 15; ++c) {
            float t = 0.0f;
            #pragma unroll
            for (int o = 0; o < 3; ++o) t = fmaf(hm[o] + ha[o], caw2[c * 3 + o], t);
            ca[c] = sigmf(t);
        }
    }
    float og[15];
    float smx = -INFINITY, ssum = 0.0f;
    #pragma unroll
    for (int c = 0; c < 15; ++c) {
        const float fv = (c < 5) ? f0[c] : (c < 10) ? f1v[c - 5] : f2v[c - 10];
        const float v = fv * ca[c];
        og[c] = v;
        smx = fmaxf(smx, v);
        ssum += v;
    }
    const float smean = ssum * (1.0f / 15.0f);
    const float sxl = __shfl_up(smx, 1, 64),   sml = __shfl_up(smean, 1, 64);
    const float sxr = __shfl_down(smx, 1, 64), smr = __shfl_down(smean, 1, 64);
    const float mskL = (tid > 0) ? 1.0f : 0.0f;
    const float mskR = (tid < NB - 1) ? 1.0f : 0.0f;
    float t = sab[0];
    t += mskL * (sxl * saw[1] + sml * saw[10]);
    t += smx * saw[4] + smean * saw[13];
    t += mskR * (sxr * saw[7] + smr * saw[16]);
    const float sa = sigmf(t);

    __syncthreads();  // adjacency dead; region becomes s_g/s_h1
    if (tid < NB) {
        #pragma unroll
        for (int c = 0; c < 15; ++c) {
            const float fv = (c < 5) ? f0[c] : (c < 10) ? f1v[c - 5] : f2v[c - 10];
            s_g[c * NB + tid] = og[c] * sa + fv;
        }
    }
    if (tid < 30) s_g[930 + tid] = 0.0f;   // zero pad to 960
    __syncthreads();

    // ================= FC head (quad-split dots, f32 weights) =================
    const int o = tid >> 2, h2 = tid & 3;
    if (use_ws) {
        float acc = (h2 == 0) ? fc1b[o] : 0.0f;
        #pragma unroll 5
        for (int j = 0; j < 30; ++j) {
            const float* wp = w1p + ((size_t)(j * 256 + tid)) * 8;
            const float4 wa = *(const float4*)wp;
            const float4 wb = *(const float4*)(wp + 4);
            const int f = h2 * 240 + j * 8;
            const float4 ga4 = *(const float4*)&s_g[f];
            const float4 gb4 = *(const float4*)&s_g[f + 4];
            acc = fmaf(wa.x, ga4.x, acc);
            acc = fmaf(wa.y, ga4.y, acc);
            acc = fmaf(wa.z, ga4.z, acc);
            acc = fmaf(wa.w, ga4.w, acc);
            acc = fmaf(wb.x, gb4.x, acc);
            acc = fmaf(wb.y, gb4.y, acc);
            acc = fmaf(wb.z, gb4.z, acc);
            acc = fmaf(wb.w, gb4.w, acc);
        }
        acc += __shfl_xor(acc, 1, 64);
        acc += __shfl_xor(acc, 2, 64);
        if (h2 == 0) s_h1[o] = fmaxf(acc, 0.0f);
        __syncthreads();
        float acc2 = (h2 == 0) ? fc2b[o] : 0.0f;
        #pragma unroll
        for (int j = 0; j < 4; ++j) {
            const float4 wv = *(const float4*)(w2p + ((size_t)(j * 256 + tid)) * 4);
            const float4 hv = *(const float4*)&s_h1[h2 * 16 + j * 4];
            acc2 = fmaf(wv.x, hv.x, acc2);
            acc2 = fmaf(wv.y, hv.y, acc2);
            acc2 = fmaf(wv.z, hv.z, acc2);
            acc2 = fmaf(wv.w, hv.w, acc2);
        }
        acc2 += __shfl_xor(acc2, 1, 64);
        acc2 += __shfl_xor(acc2, 2, 64);
        if (h2 == 0) g_out[(size_t)b * 64 + o] = fmaxf(acc2, 0.0f);
    } else {
        // fallback: h2==0 lane does the full (uncoalesced) dot
        float acc = 0.0f;
        if (h2 == 0) {
            acc = fc1b[o];
            const float* wr = fc1w + (size_t)o * 930;
            for (int i = 0; i < 930; i += 2)
                acc = fmaf(wr[i], s_g[i], fmaf(wr[i + 1], s_g[i + 1], acc));
            s_h1[o] = fmaxf(acc, 0.0f);
        }
        __syncthreads();
        if (h2 == 0) {
            float acc2 = fc2b[o];
            const float* wr2 = fc2w + o * 64;
            for (int k = 0; k < 64; ++k) acc2 = fmaf(wr2[k], s_h1[k], acc2);
            g_out[(size_t)b * 64 + o] = fmaxf(acc2, 0.0f);
        }
    }
}

extern "C" void kernel_launch(void* const* d_in, const int* in_sizes, int n_in,
                              void* d_out, int out_size, void* d_ws, size_t ws_size,
                              hipStream_t stream) {
    const float* X    = (const float*)d_in[0];
    const float* C0W  = (const float*)d_in[1];
    const float* C0B  = (const float*)d_in[2];
    const float* M0   = (const float*)d_in[3];
    const float* F0W  = (const float*)d_in[4];
    const float* F0B  = (const float*)d_in[5];
    const float* G0W  = (const float*)d_in[6];
    const float* G0B  = (const float*)d_in[7];
    const float* C1W  = (const float*)d_in[8];
    const float* C1B  = (const float*)d_in[9];
    const float* M1   = (const float*)d_in[10];
    const float* F1W  = (const float*)d_in[11];
    const float* F1B  = (const float*)d_in[12];
    const float* G1W  = (const float*)d_in[13];
    const float* G1B  = (const float*)d_in[14];
    const float* CAW1 = (const float*)d_in[15];
    const float* CAW2 = (const float*)d_in[16];
    const float* SAW  = (const float*)d_in[17];
    const float* SAB  = (const float*)d_in[18];
    const float* FC1W = (const float*)d_in[19];
    const float* FC1B = (const float*)d_in[20];
    const float* FC2W = (const float*)d_in[21];
    const float* FC2B = (const float*)d_in[22];

    const int B = in_sizes[0] / (NC * NB);

    const size_t W1_BYTES = 30 * 256 * 8 * sizeof(float);  // 245760
    const size_t W2_BYTES = 4 * 256 * 4 * sizeof(float);   // 16384
    const int use_ws = (ws_size >= W1_BYTES + W2_BYTES) ? 1 : 0;
    float* w1p = (float*)d_ws;
    float* w2p = (float*)((char*)d_ws + W1_BYTES);

    if (use_ws) {
        repack_kernel<<<256, 256, 0, stream>>>(FC1W, FC2W, w1p, w2p);
    }

    encoder_kernel<<<B, 256, 0, stream>>>(
        X, C0W, C0B, M0, F0W, F0B, G0W, G0B,
        C1W, C1B, M1, F1W, F1B, G1W, G1B,
        CAW1, CAW2, SAW, SAB, FC1W, FC1B, FC2W, FC2B,
        w1p, w2p, use_ws,
        (float*)d_out);
}

// Round 13
// 215.650 us; speedup vs baseline: 1.7325x; 1.7325x over previous
//
#include <hip/hip_runtime.h>

#define NB 62
#define NC 5
#define KTOP 49

typedef unsigned short ushort_t;
typedef unsigned int uint_t;

__device__ __forceinline__ float sigmf(float x) {
    return 1.0f / (1.0f + __expf(-x));
}

__device__ __forceinline__ ushort_t f2b(float f) {   // f32 -> bf16 (RNE)
    union { float f; uint_t u; } cv; cv.f = f;
    uint_t r = (cv.u + 0x7fffu + ((cv.u >> 16) & 1u)) >> 16;
    return (ushort_t)r;
}
__device__ __forceinline__ float bits2f(uint_t u) {
    union { uint_t u; float f; } cv; cv.u = u; return cv.f;
}

__device__ __forceinline__ float tmax62(const float* a) {
    float t0 = a[0], t1 = a[1], t2 = a[2], t3 = a[3];
    #pragma unroll
    for (int m = 4; m < 60; m += 4) {
        t0 = fmaxf(t0, a[m]);     t1 = fmaxf(t1, a[m + 1]);
        t2 = fmaxf(t2, a[m + 2]); t3 = fmaxf(t3, a[m + 3]);
    }
    t0 = fmaxf(t0, a[60]); t1 = fmaxf(t1, a[61]);
    return fmaxf(fmaxf(t0, t1), fmaxf(t2, t3));
}
__device__ __forceinline__ float tsum62(const float* a) {
    float t0 = a[0], t1 = a[1], t2 = a[2], t3 = a[3];
    #pragma unroll
    for (int m = 4; m < 60; m += 4) {
        t0 += a[m]; t1 += a[m + 1]; t2 += a[m + 2]; t3 += a[m + 3];
    }
    t0 += a[60]; t1 += a[61];
    return (t0 + t1) + (t2 + t3);
}

// ascending bitonic sort of 16 register-resident floats
__device__ __forceinline__ void sort16(float* s) {
    #pragma unroll
    for (int k = 2; k <= 16; k <<= 1) {
        #pragma unroll
        for (int j = k >> 1; j > 0; j >>= 1) {
            #pragma unroll
            for (int i = 0; i < 16; ++i) {
                const int p = i ^ j;
                if (p > i) {
                    const bool up = ((i & k) == 0);
                    const float a = s[i], c = s[p];
                    s[i] = up ? fminf(a, c) : fmaxf(a, c);
                    s[p] = up ? fmaxf(a, c) : fminf(a, c);
                }
            }
        }
    }
}
// m asc, b asc -> m = 16 smallest of union, ascending
__device__ __forceinline__ void merge_low16(float* m, const float* b) {
    float t[16];
    #pragma unroll
    for (int i = 0; i < 16; ++i) t[i] = fminf(m[i], b[15 - i]);
    #pragma unroll
    for (int j = 8; j > 0; j >>= 1) {
        #pragma unroll
        for (int i = 0; i < 16; ++i) {
            const int p = i ^ j;
            if (p > i) {
                const float a = t[i], c = t[p];
                t[i] = fminf(a, c);
                t[p] = fmaxf(a, c);
            }
        }
    }
    #pragma unroll
    for (int i = 0; i < 16; ++i) m[i] = t[i];
}

// Repack FC weights (f32 -> no unpack VALU in main kernel):
// fc1w[64][930] -> [117][64][8]: [j][t][e] = fc1w[t][j*8+e], zero-pad past 929.
// fc2w[64][64]  -> [16][64][4]:  [k4][o][e] = fc2w[o][k4*4+e].
__global__ void repack_kernel(const float* __restrict__ fc1w,
                              const float* __restrict__ fc2w,
                              float* __restrict__ w1o,
                              float* __restrict__ w2o) {
    const int i = blockIdx.x * 256 + threadIdx.x;
    if (i < 117 * 64 * 8) {
        const int e = i & 7, t = (i >> 3) & 63, j = i >> 9;
        const int src = j * 8 + e;
        w1o[i] = (src < 930) ? fc1w[t * 930 + src] : 0.0f;
    } else if (i < 117 * 64 * 8 + 16 * 64 * 4) {
        const int i2 = i - 117 * 64 * 8;
        const int e = i2 & 3, o = (i2 >> 2) & 63, k4 = i2 >> 8;
        w2o[i2] = fc2w[o * 64 + k4 * 4 + e];
    }
}

// One DGCN layer (1 thread = 1 row). L==0: input = global x[b] (re-read
// phase-locally, never live across selection); out -> s_x1. L==1: in s_x1,
// out -> f2out regs. mem is STAGED IN LDS (round-8 regression traced to
// per-iteration wave-uniform global scalar loads; LDS broadcast is stall-free).
template <int L>
__device__ __forceinline__ void dgcn_layer(
    const int tid, const float* __restrict__ xin_g,
    const float* __restrict__ conv_w, const float* __restrict__ conv_b,
    const float* __restrict__ memp,
    const float* __restrict__ gfc_w, const float* __restrict__ gfc_b,
    const float* __restrict__ gcn_w, const float* __restrict__ gcn_b,
    float (*__restrict__ s_xc4)[4], float* __restrict__ s_xc1,
    float (*__restrict__ s_me4)[4], float* __restrict__ s_me1,
    uint_t* __restrict__ s_adj32,
    float (*__restrict__ s_x1)[NC], float* __restrict__ f2out)
{
    const float scale = 0.44721359549995793f; // 1/sqrt(5)

    // stage mem (310 floats, 64 threads strided)
    for (int i = tid; i < NC * NB; i += 64) {
        const int c = i / NB, m = i - c * NB;
        if (c < 4) s_me4[m][c] = memp[i];
        else       s_me1[m]    = memp[i];
    }

    float cw[25], cbv[5];
    #pragma unroll
    for (int i = 0; i < 25; ++i) cw[i] = conv_w[i];
    #pragma unroll
    for (int i = 0; i < 5; ++i)  cbv[i] = conv_b[i];
    const float w0 = gfc_w[0], w1 = gfc_w[1], b0 = gfc_b[0];

    // ---- conv1x1 on own node (input regs die before the selection) ----
    float xo0 = 0, xo1 = 0, xo2 = 0, xo3 = 0, xo4 = 0;
    if (tid < NB) {
        float xn[5];
        #pragma unroll
        for (int c = 0; c < 5; ++c)
            xn[c] = (L == 0) ? xin_g[c * NB + tid] : s_x1[tid][c];
        xo0 = cbv[0]; xo1 = cbv[1]; xo2 = cbv[2]; xo3 = cbv[3]; xo4 = cbv[4];
        #pragma unroll
        for (int c = 0; c < 5; ++c) {
            xo0 = fmaf(cw[c],      xn[c], xo0);
            xo1 = fmaf(cw[5 + c],  xn[c], xo1);
            xo2 = fmaf(cw[10 + c], xn[c], xo2);
            xo3 = fmaf(cw[15 + c], xn[c], xo3);
            xo4 = fmaf(cw[20 + c], xn[c], xo4);
        }
        s_xc4[tid][0] = xo0; s_xc4[tid][1] = xo1;
        s_xc4[tid][2] = xo2; s_xc4[tid][3] = xo3;
        s_xc1[tid] = xo4;
    }
    __syncthreads();

    // ---- row phase: thread n owns row n (all LDS reads are broadcasts) ----
    if (tid < NB) {
        float r1[NB];
        float r2[NB];
        #pragma unroll
        for (int m = 0; m < NB; ++m) {
            const float4 xc03 = *(const float4*)&s_xc4[m][0];
            const float  xc4  = s_xc1[m];
            const float4 me03 = *(const float4*)&s_me4[m][0];
            const float  me4  = s_me1[m];
            float s1 = xo0 * me03.x + xo1 * me03.y + xo2 * me03.z + xo3 * me03.w + xo4 * me4;
            float s2 = xo0 * xc03.x + xo1 * xc03.y + xo2 * xc03.z + xo3 * xc03.w + xo4 * xc4;
            r1[m] = fmaxf(s1 * scale, 0.0f);
            r2[m] = fmaxf(s2 * scale, 0.0f);
        }
        const float mx1 = tmax62(r1);
        #pragma unroll
        for (int m = 0; m < NB; ++m) r1[m] = __expf(r1[m] - mx1);
        const float inv1 = 1.0f / tsum62(r1);
        const float mx2 = tmax62(r2);
        #pragma unroll
        for (int m = 0; m < NB; ++m) r2[m] = __expf(r2[m] - mx2);
        const float inv2 = 1.0f / tsum62(r2);
        #pragma unroll
        for (int m = 0; m < NB; ++m)
            r1[m] = b0 + (r1[m] * inv1) * w0 + (r2[m] * inv2) * w1;   // r2 dies
        const float mxa = tmax62(r1);
        #pragma unroll
        for (int m = 0; m < NB; ++m) r1[m] = __expf(r1[m] - mxa);
        const float inva = 1.0f / tsum62(r1);
        #pragma unroll
        for (int m = 0; m < NB; ++m) r1[m] *= inva;

        // ---- 49th-largest (=14th-smallest) via partial selection network:
        //      4x sort16 + 3x keep-lowest-16 merge (exact vth; peak extra
        //      live 32 regs vs 64 for a full sort) ----
        float ga[16], gb[16];
        #pragma unroll
        for (int i = 0; i < 16; ++i) ga[i] = r1[i];
        sort16(ga);
        #pragma unroll
        for (int i = 0; i < 16; ++i) gb[i] = r1[16 + i];
        sort16(gb);
        merge_low16(ga, gb);
        #pragma unroll
        for (int i = 0; i < 16; ++i) gb[i] = r1[32 + i];
        sort16(gb);
        merge_low16(ga, gb);
        #pragma unroll
        for (int i = 0; i < 14; ++i) gb[i] = r1[48 + i];
        gb[14] = INFINITY; gb[15] = INFINITY;
        sort16(gb);
        merge_low16(ga, gb);
        const float vth = ga[13];   // 14th smallest == 49th largest

        // ---- tie-aware selection == jax.lax.top_k (lower index first) ----
        int gc0 = 0, gc1 = 0, gc2 = 0, gc3 = 0;
        #pragma unroll
        for (int m = 0; m < 60; m += 4) {
            gc0 += (r1[m] > vth);     gc1 += (r1[m + 1] > vth);
            gc2 += (r1[m + 2] > vth); gc3 += (r1[m + 3] > vth);
        }
        gc0 += (r1[60] > vth); gc1 += (r1[61] > vth);
        const int G = (gc0 + gc1) + (gc2 + gc3);
        int eq = 0;
        uint_t pend = 0;
        #pragma unroll
        for (int m = 0; m < NB; ++m) {
            const bool e  = (r1[m] == vth);
            const bool ss = (r1[m] > vth) || (e && (G + eq) < KTOP);
            const uint_t h = (uint_t)f2b(ss ? r1[m] : 0.0f);
            if (m & 1) s_adj32[tid * 31 + (m >> 1)] = pend | (h << 16);
            else       pend = h;
            eq += e ? 1 : 0;
        }
    }
    __syncthreads();

    // ---- diffusion + gcn mix + skip: thread m computes output column m ----
    if (tid < NB) {
        const int m = tid;
        const int dw = m >> 1;
        const uint_t sh = (m & 1) ? 16u : 0u;
        float y0 = 0, y1 = 0, y2 = 0, y3 = 0, y4 = 0;
        for (int n = 0; n < NB; ++n) {
            // stride 31 dwords (odd): 62 lanes -> 31 consecutive dwords,
            // 2 lanes/dword same-address broadcast -> conflict-free (r8: 0)
            const uint_t w = s_adj32[n * 31 + dw];
            const float a = bits2f((w >> sh) << 16);
            const float4 xv = *(const float4*)&s_xc4[n][0];
            const float  xv4 = s_xc1[n];
            y0 = fmaf(xv.x, a, y0); y1 = fmaf(xv.y, a, y1); y2 = fmaf(xv.z, a, y2);
            y3 = fmaf(xv.w, a, y3); y4 = fmaf(xv4, a, y4);
        }
        float gwv[25], gbv[5];
        #pragma unroll
        for (int i = 0; i < 25; ++i) gwv[i] = gcn_w[i];
        #pragma unroll
        for (int i = 0; i < 5; ++i)  gbv[i] = gcn_b[i];
        #pragma unroll
        for (int o = 0; o < 5; ++o) {
            const float z = gbv[o] + gwv[o * 5 + 0] * y0 + gwv[o * 5 + 1] * y1 +
                            gwv[o * 5 + 2] * y2 + gwv[o * 5 + 3] * y3 + gwv[o * 5 + 4] * y4;
            const float fi = (L == 0) ? xin_g[o * NB + m] : s_x1[m][o];
            const float zz = z + fi;
            if (L == 0) s_x1[m][o] = zz;
            else        f2out[o]   = zz;
        }
    }
    __syncthreads();
}

// waves_per_eu(2,3): the R6/R8-proven codegen range (84-88 VGPR, small
// L1-contained spills). LDS 11408 B -> 13 blocks/CU, matching R6 (215 us).
__global__ void __launch_bounds__(64) __attribute__((amdgpu_waves_per_eu(2, 3)))
encoder_kernel(
    const float* __restrict__ g_x,
    const float* __restrict__ c0w, const float* __restrict__ c0b,
    const float* __restrict__ m0,  const float* __restrict__ f0w,
    const float* __restrict__ f0b, const float* __restrict__ g0w,
    const float* __restrict__ g0b,
    const float* __restrict__ c1w, const float* __restrict__ c1b,
    const float* __restrict__ m1,  const float* __restrict__ f1w,
    const float* __restrict__ f1b, const float* __restrict__ g1w,
    const float* __restrict__ g1b,
    const float* __restrict__ caw1, const float* __restrict__ caw2,
    const float* __restrict__ saw,  const float* __restrict__ sab,
    const float* __restrict__ fc1w, const float* __restrict__ fc1b,
    const float* __restrict__ fc2w, const float* __restrict__ fc2b,
    const float* __restrict__ w1p, const float* __restrict__ w2p,
    const int use_ws,
    float* __restrict__ g_out)
{
    const int b   = blockIdx.x;
    const int tid = threadIdx.x;

    // LDS: 992 + 248 + 992 + 248 + 7688 + 1240 = 11408 B
    __shared__ __align__(16) float s_xc4[NB][4];
    __shared__ __align__(16) float s_xc1[NB];
    __shared__ __align__(16) float s_me4[NB][4];
    __shared__ __align__(16) float s_me1[NB];
    __shared__ __align__(16) uint_t s_adj32[NB * 31];
    __shared__ __align__(16) float s_x1[NB][NC];

    float* const s_g  = (float*)s_adj32;        // 936 f32 alias (adjacency dead)
    float* const s_h1 = ((float*)s_adj32) + 936;

    const float* xin = g_x + (size_t)b * (NC * NB);

    float f2[5] = {0, 0, 0, 0, 0};
    dgcn_layer<0>(tid, xin, c0w, c0b, m0, f0w, f0b, g0w, g0b,
                  s_xc4, s_xc1, s_me4, s_me1, s_adj32, s_x1, nullptr);
    dgcn_layer<1>(tid, xin, c1w, c1b, m1, f1w, f1b, g1w, g1b,
                  s_xc4, s_xc1, s_me4, s_me1, s_adj32, s_x1, f2);

    // ================= CBAM (shuffle-based, all post-selection) ==============
    float f0[5], f1v[5];
    #pragma unroll
    for (int c = 0; c < 5; ++c) {
        f0[c]  = (tid < NB) ? xin[c * NB + tid] : 0.0f;
        f1v[c] = (tid < NB) ? s_x1[tid][c] : 0.0f;
    }

    float mxp[15], avp[15];
    #pragma unroll
    for (int c = 0; c < 15; ++c) {
        const float v = (c < 5) ? f0[c] : (c < 10) ? f1v[c - 5] : f2[c - 10];
        float vm = (tid < NB) ? v : -INFINITY;
        float vs = (tid < NB) ? v : 0.0f;
        #pragma unroll
        for (int off = 32; off > 0; off >>= 1) {
            vm = fmaxf(vm, __shfl_xor(vm, off, 64));
            vs += __shfl_xor(vs, off, 64);
        }
        mxp[c] = vm;
        avp[c] = vs * (1.0f / 62.0f);
    }
    float ca[15];
    {
        float hm[3], ha[3];
        #pragma unroll
        for (int o = 0; o < 3; ++o) {
            float am = 0.0f, aa = 0.0f;
            #pragma unroll
            for (int c = 0; c < 15; ++c) {
                const float w = caw1[o * 15 + c];
                am = fmaf(mxp[c], w, am);
                aa = fmaf(avp[c], w, aa);
            }
            hm[o] = fmaxf(am, 0.0f);
            ha[o] = fmaxf(aa, 0.0f);
        }
        #pragma unroll
        for (int c = 0; c < 15; ++c) {
            float t = 0.0f;
            #pragma unroll
            for (int o = 0; o < 3; ++o) t = fmaf(hm[o] + ha[o], caw2[c * 3 + o], t);
            ca[c] = sigmf(t);
        }
    }
    float og[15];
    float smx = -INFINITY, ssum = 0.0f;
    #pragma unroll
    for (int c = 0; c < 15; ++c) {
        const float fv = (c < 5) ? f0[c] : (c < 10) ? f1v[c - 5] : f2[c - 10];
        const float v = fv * ca[c];
        og[c] = v;
        smx = fmaxf(smx, v);
        ssum += v;
    }
    const float smean = ssum * (1.0f / 15.0f);
    const float sxl = __shfl_up(smx, 1, 64),   sml = __shfl_up(smean, 1, 64);
    const float sxr = __shfl_down(smx, 1, 64), smr = __shfl_down(smean, 1, 64);
    const float mskL = (tid > 0) ? 1.0f : 0.0f;
    const float mskR = (tid < NB - 1) ? 1.0f : 0.0f;
    float t = sab[0];
    t += mskL * (sxl * saw[1] + sml * saw[10]);
    t += smx * saw[4] + smean * saw[13];
    t += mskR * (sxr * saw[7] + smr * saw[16]);
    const float sa = sigmf(t);

    __syncthreads();  // adjacency dead; region becomes s_g/s_h1
    if (tid < NB) {
        #pragma unroll
        for (int c = 0; c < 15; ++c) {
            const float fv = (c < 5) ? f0[c] : (c < 10) ? f1v[c - 5] : f2[c - 10];
            s_g[c * NB + tid] = og[c] * sa + fv;
        }
    }
    if (tid < 6) s_g[930 + tid] = 0.0f;   // zero pad to 936
    __syncthreads();

    // ================= FC head (f32 repacked weights) =================
    if (use_ws) {
        float acc = fc1b[tid];
        #pragma unroll 4
        for (int j = 0; j < 117; ++j) {
            const float* wp = w1p + ((size_t)(j * 64 + tid)) * 8;
            const float4 wa = *(const float4*)wp;
            const float4 wb = *(const float4*)(wp + 4);
            const float4 ga4 = *(const float4*)&s_g[j * 8];
            const float4 gb4 = *(const float4*)&s_g[j * 8 + 4];
            acc = fmaf(wa.x, ga4.x, acc);
            acc = fmaf(wa.y, ga4.y, acc);
            acc = fmaf(wa.z, ga4.z, acc);
            acc = fmaf(wa.w, ga4.w, acc);
            acc = fmaf(wb.x, gb4.x, acc);
            acc = fmaf(wb.y, gb4.y, acc);
            acc = fmaf(wb.z, gb4.z, acc);
            acc = fmaf(wb.w, gb4.w, acc);
        }
        s_h1[tid] = fmaxf(acc, 0.0f);
        __syncthreads();
        float acc2 = fc2b[tid];
        #pragma unroll
        for (int k4 = 0; k4 < 16; ++k4) {
            const float4 wv = *(const float4*)(w2p + (k4 * 64 + tid) * 4);
            const float4 hv = *(const float4*)&s_h1[k4 * 4];
            acc2 = fmaf(wv.x, hv.x, acc2);
            acc2 = fmaf(wv.y, hv.y, acc2);
            acc2 = fmaf(wv.z, hv.z, acc2);
            acc2 = fmaf(wv.w, hv.w, acc2);
        }
        g_out[(size_t)b * 64 + tid] = fmaxf(acc2, 0.0f);
    } else {
        float acc = fc1b[tid];
        const float* wr = fc1w + (size_t)tid * 930;
        #pragma unroll 4
        for (int i = 0; i < 928; i += 2) {
            const float2 wv = *(const float2*)(wr + i);
            const float2 gv = *(const float2*)(&s_g[i]);
            acc = fmaf(wv.x, gv.x, fmaf(wv.y, gv.y, acc));
        }
        acc += wr[928] * s_g[928] + wr[929] * s_g[929];
        s_h1[tid] = fmaxf(acc, 0.0f);
        __syncthreads();
        float acc2 = fc2b[tid];
        const float* wr2 = fc2w + tid * 64;
        #pragma unroll
        for (int k = 0; k < 64; k += 4) {
            const float4 wv = *(const float4*)(wr2 + k);
            acc2 = fmaf(wv.x, s_h1[k], acc2);
            acc2 = fmaf(wv.y, s_h1[k + 1], acc2);
            acc2 = fmaf(wv.z, s_h1[k + 2], acc2);
            acc2 = fmaf(wv.w, s_h1[k + 3], acc2);
        }
        g_out[(size_t)b * 64 + tid] = fmaxf(acc2, 0.0f);
    }
}

extern "C" void kernel_launch(void* const* d_in, const int* in_sizes, int n_in,
                              void* d_out, int out_size, void* d_ws, size_t ws_size,
                              hipStream_t stream) {
    const float* X    = (const float*)d_in[0];
    const float* C0W  = (const float*)d_in[1];
    const float* C0B  = (const float*)d_in[2];
    const float* M0   = (const float*)d_in[3];
    const float* F0W  = (const float*)d_in[4];
    const float* F0B  = (const float*)d_in[5];
    const float* G0W  = (const float*)d_in[6];
    const float* G0B  = (const float*)d_in[7];
    const float* C1W  = (const float*)d_in[8];
    const float* C1B  = (const float*)d_in[9];
    const float* M1   = (const float*)d_in[10];
    const float* F1W  = (const float*)d_in[11];
    const float* F1B  = (const float*)d_in[12];
    const float* G1W  = (const float*)d_in[13];
    const float* G1B  = (const float*)d_in[14];
    const float* CAW1 = (const float*)d_in[15];
    const float* CAW2 = (const float*)d_in[16];
    const float* SAW  = (const float*)d_in[17];
    const float* SAB  = (const float*)d_in[18];
    const float* FC1W = (const float*)d_in[19];
    const float* FC1B = (const float*)d_in[20];
    const float* FC2W = (const float*)d_in[21];
    const float* FC2B = (const float*)d_in[22];

    const int B = in_sizes[0] / (NC * NB);

    const size_t W1_BYTES = 117 * 64 * 8 * sizeof(float);  // 239616
    const size_t W2_BYTES = 16 * 64 * 4 * sizeof(float);   // 16384
    const int use_ws = (ws_size >= W1_BYTES + W2_BYTES) ? 1 : 0;
    float* w1p = (float*)d_ws;
    float* w2p = (float*)((char*)d_ws + W1_BYTES);

    if (use_ws) {
        repack_kernel<<<250, 256, 0, stream>>>(FC1W, FC2W, w1p, w2p);
    }

    encoder_kernel<<<B, 64, 0, stream>>>(
        X, C0W, C0B, M0, F0W, F0B, G0W, G0B,
        C1W, C1B, M1, F1W, F1B, G1W, G1B,
        CAW1, CAW2, SAW, SAB, FC1W, FC1B, FC2W, FC2B,
        w1p, w2p, use_ws,
        (float*)d_out);
}